// Round 5
// baseline (300.935 us; speedup 1.0000x reference)
//
#include <hip/hip_runtime.h>

#define OUTN 8192
#define INN  4096
#define BN   128

namespace {

typedef __attribute__((ext_vector_type(8))) short bf16x8;   // 8 bf16 (4 VGPRs)
typedef __attribute__((ext_vector_type(4))) float f32x4;

struct alignas(16) f4 { float v[4]; };
struct alignas(8)  h4 { short v[4]; };

constexpr float C_HLOG2PI = 0.91893853f;   // 0.5*log(2*pi)

__device__ __forceinline__ short f2bf(float f) {
    unsigned u = __float_as_uint(f);
    u += 0x7fffu + ((u >> 16) & 1u);       // round-to-nearest-even
    return (short)(u >> 16);
}

// ---- full-form helpers (tiny bias kernel only) ----
__device__ __forceinline__ float prior_lp(float w) {
    float lp1 = -0.5f * w * w - C_HLOG2PI;
    float a   = w * 400.0f;
    float lp2 = -0.5f * a * a + 5.0725261f;
    return __logf(0.5f * __expf(lp1) + 0.5f * __expf(lp2));
}
__device__ __forceinline__ float post_lp(float w, float pi_, float s1, float ls1,
                                         float s2, float ls2) {
    float u1  = __fdividef(w, s1);
    float u2  = __fdividef(w, s2);
    float lq1 = -0.5f * u1 * u1 - ls1 - C_HLOG2PI;
    float lq2 = -0.5f * u2 * u2 - ls2 - C_HLOG2PI;
    return __logf(pi_ * __expf(lq1) + (1.0f - pi_) * __expf(lq2));
}
__device__ __forceinline__ float sample_w(float pi_, float rho1, float rho2, float ep,
                                          float g0, float g1,
                                          float& s1, float& ls1, float& s2, float& ls2) {
    s1  = __logf(1.0f + __expf(rho1));
    s2  = __logf(1.0f + __expf(rho2));
    ls1 = __logf(s1);
    ls2 = __logf(s2);
    bool mode1 = ((1.0f - pi_) + g1) > (pi_ + g0);
    return (mode1 ? s1 : s2) * ep;
}

constexpr int KC = 32;    // K per chunk (== MFMA K)

__global__ __launch_bounds__(256)
void xcast(const float* __restrict__ x, short* __restrict__ xb)
{
    const int i = (blockIdx.x * 256 + threadIdx.x) * 8;   // 256 blocks
    f4 a = *(const f4*)&x[i];
    f4 b = *(const f4*)&x[i + 4];
    h4 o0, o1;
    #pragma unroll
    for (int j = 0; j < 4; ++j) { o0.v[j] = f2bf(a.v[j]); o1.v[j] = f2bf(b.v[j]); }
    *(h4*)&xb[i]     = o0;
    *(h4*)&xb[i + 4] = o1;
}

// One wave per block. Wave owns 16 output cols (o-group) x all 128 batch rows
// x a K-slice. Each lane samples exactly its own MFMA B-fragment elements:
// lane l -> o = o_base + (l&15), k = kb + (l>>4)*8 + j, j=0..7.
// No LDS, no barriers.
__global__ __launch_bounds__(64, 4)
void bayes_main(const short* __restrict__ xb,      // x in bf16, [BN][INN]
                const float* __restrict__ w_pi,
                const float* __restrict__ w_rho1,
                const float* __restrict__ w_rho2,
                const float* __restrict__ eps_w,
                const float* __restrict__ gum_w,
                const float* __restrict__ bias,    // non-null only when nsplit==1
                float* __restrict__ out,
                float* __restrict__ pbuf,
                float* __restrict__ partials,
                int kps)
{
    const int blk   = blockIdx.x;
    const int og    = blk & 511;          // 512 o-groups
    const int split = blk >> 9;
    const int o0    = og * 16;
    const int k0    = split * kps;
    const int nch   = kps / KC;
    float* outp = (split == 0) ? out : pbuf + (size_t)(split - 1) * ((size_t)BN * OUTN);

    const int lane = threadIdx.x;         // 0..63
    const int lrow = lane & 15;           // o within group / x-row within m-tile
    const int q8   = (lane >> 4) * 8;     // k-slot base

    const int    orow = o0 + lrow;
    const size_t idx  = (size_t)orow * INN + (size_t)(k0 + q8);
    const f4* pi4 = (const f4*)(w_pi   + idx);
    const f4* r14 = (const f4*)(w_rho1 + idx);
    const f4* r24 = (const f4*)(w_rho2 + idx);
    const f4* ep4 = (const f4*)(eps_w  + idx);
    const f4* gm4 = (const f4*)(gum_w  + 2 * idx);
    const short* xrow = xb + (size_t)lrow * INN + (size_t)(k0 + q8);

    f32x4 acc0 = {0,0,0,0}, acc1 = {0,0,0,0}, acc2 = {0,0,0,0}, acc3 = {0,0,0,0};
    f32x4 acc4 = {0,0,0,0}, acc5 = {0,0,0,0}, acc6 = {0,0,0,0}, acc7 = {0,0,0,0};
    float priorAcc = 0.0f, postAcc = 0.0f;

    constexpr size_t MS = (size_t)16 * INN;   // m-tile row stride (shorts)

    // prologue: stage streams chunk 0 + first two A-frags
    f4 p0 = pi4[0], p1 = pi4[1];
    f4 u0 = r14[0], u1 = r14[1];
    f4 v0 = r24[0], v1 = r24[1];
    f4 e0 = ep4[0], e1 = ep4[1];
    f4 g0 = gm4[0], g1 = gm4[1], g2 = gm4[2], g3 = gm4[3];
    bf16x8 a0 = *(const bf16x8*)(xrow);
    bf16x8 a1 = *(const bf16x8*)(xrow + MS);

    #pragma unroll 1
    for (int t = 0; t < nch; ++t) {
        // --- sample this lane's 8 B-frag elements + log-probs ---
        bf16x8 wfrag;
        #pragma unroll
        for (int j = 0; j < 8; ++j) {
            float pi_ = ((j < 4) ? p0 : p1).v[j & 3];
            float rh1 = ((j < 4) ? u0 : u1).v[j & 3];
            float rh2 = ((j < 4) ? v0 : v1).v[j & 3];
            float ep  = ((j < 4) ? e0 : e1).v[j & 3];
            const f4& gg = (j < 2) ? g0 : (j < 4) ? g1 : (j < 6) ? g2 : g3;
            float gg0 = gg.v[(j & 1) * 2], gg1 = gg.v[(j & 1) * 2 + 1];

            float s1  = __logf(1.0f + __expf(rh1));
            float s2  = __logf(1.0f + __expf(rh2));
            float ls1 = __logf(s1), ls2 = __logf(s2);
            bool  m1  = ((1.0f - pi_) + gg1) > (pi_ + gg0);
            float sm  = m1 ? s1 : s2;
            float so  = m1 ? s2 : s1;
            float lsm = m1 ? ls1 : ls2;
            float lso = m1 ? ls2 : ls1;
            float wm  = m1 ? pi_ : 1.0f - pi_;
            float w   = sm * ep;
            wfrag[j] = f2bf(w);
            float wsq = w * w;
            float dlp = 5.9914645f - 79999.5f * wsq;
            priorAcc += -0.5f * wsq - C_HLOG2PI + __logf(0.5f + 0.5f * __expf(dlp));
            float uo   = __fdividef(w, so);
            float epsq = ep * ep;
            float dlq  = 0.5f * (epsq - uo * uo) + (lsm - lso);
            postAcc += -0.5f * epsq - lsm - C_HLOG2PI
                       + __logf(wm + (1.0f - wm) * __expf(dlq));
        }

        // --- prefetch streams for t+1 (latency hides under MFMA + next issue) ---
        const int tn = (t + 1 < nch) ? t + 1 : t;
        p0 = pi4[8*tn]; p1 = pi4[8*tn + 1];
        u0 = r14[8*tn]; u1 = r14[8*tn + 1];
        v0 = r24[8*tn]; v1 = r24[8*tn + 1];
        e0 = ep4[8*tn]; e1 = ep4[8*tn + 1];
        g0 = gm4[16*tn]; g1 = gm4[16*tn + 1]; g2 = gm4[16*tn + 2]; g3 = gm4[16*tn + 3];

        // --- MFMA phase: 8 m-tiles (M=128), 2-deep A pipeline ---
        const short* xc = xrow + 32 * t;
        const short* xn = xrow + 32 * tn;
        bf16x8 t2 = *(const bf16x8*)(xc + 2 * MS);
        bf16x8 t3 = *(const bf16x8*)(xc + 3 * MS);
        acc0 = __builtin_amdgcn_mfma_f32_16x16x32_bf16(a0, wfrag, acc0, 0, 0, 0);
        bf16x8 t4 = *(const bf16x8*)(xc + 4 * MS);
        acc1 = __builtin_amdgcn_mfma_f32_16x16x32_bf16(a1, wfrag, acc1, 0, 0, 0);
        bf16x8 t5 = *(const bf16x8*)(xc + 5 * MS);
        acc2 = __builtin_amdgcn_mfma_f32_16x16x32_bf16(t2, wfrag, acc2, 0, 0, 0);
        bf16x8 t6 = *(const bf16x8*)(xc + 6 * MS);
        acc3 = __builtin_amdgcn_mfma_f32_16x16x32_bf16(t3, wfrag, acc3, 0, 0, 0);
        bf16x8 t7 = *(const bf16x8*)(xc + 7 * MS);
        acc4 = __builtin_amdgcn_mfma_f32_16x16x32_bf16(t4, wfrag, acc4, 0, 0, 0);
        a0 = *(const bf16x8*)(xn);            // next-chunk A prefetch
        acc5 = __builtin_amdgcn_mfma_f32_16x16x32_bf16(t5, wfrag, acc5, 0, 0, 0);
        a1 = *(const bf16x8*)(xn + MS);
        acc6 = __builtin_amdgcn_mfma_f32_16x16x32_bf16(t6, wfrag, acc6, 0, 0, 0);
        acc7 = __builtin_amdgcn_mfma_f32_16x16x32_bf16(t7, wfrag, acc7, 0, 0, 0);
    }

    // epilogue: D layout col = lane&15 (o), row = (lane>>4)*4 + j (b within m-tile)
    {
        const int   bq  = (lane >> 4) * 4;
        const float bv  = bias ? bias[orow] : 0.0f;
        #pragma unroll
        for (int j = 0; j < 4; ++j) {
            outp[(size_t)(  0 + bq + j) * OUTN + orow] = acc0[j] + bv;
            outp[(size_t)( 16 + bq + j) * OUTN + orow] = acc1[j] + bv;
            outp[(size_t)( 32 + bq + j) * OUTN + orow] = acc2[j] + bv;
            outp[(size_t)( 48 + bq + j) * OUTN + orow] = acc3[j] + bv;
            outp[(size_t)( 64 + bq + j) * OUTN + orow] = acc4[j] + bv;
            outp[(size_t)( 80 + bq + j) * OUTN + orow] = acc5[j] + bv;
            outp[(size_t)( 96 + bq + j) * OUTN + orow] = acc6[j] + bv;
            outp[(size_t)(112 + bq + j) * OUTN + orow] = acc7[j] + bv;
        }
    }

    // wave reduction of log-prob partials (deterministic)
    #pragma unroll
    for (int off = 32; off; off >>= 1) {
        priorAcc += __shfl_down(priorAcc, off);
        postAcc  += __shfl_down(postAcc, off);
    }
    if (lane == 0) {
        partials[2*blk    ] = priorAcc;
        partials[2*blk + 1] = postAcc;
    }
}

__global__ __launch_bounds__(256)
void bayes_bias(const float* __restrict__ b_pi, const float* __restrict__ b_rho1,
                const float* __restrict__ b_rho2, const float* __restrict__ eps_b,
                const float* __restrict__ gum_b,
                float* __restrict__ bias_vals, float* __restrict__ bpart)
{
    __shared__ float red[8];
    const int tid = threadIdx.x;
    const int o = blockIdx.x * 256 + tid;      // 32 blocks x 256 = 8192
    float pi_ = b_pi[o], rho1 = b_rho1[o], rho2 = b_rho2[o], ep = eps_b[o];
    float g0 = gum_b[2*o], g1 = gum_b[2*o + 1];
    float s1, ls1, s2, ls2;
    float w = sample_w(pi_, rho1, rho2, ep, g0, g1, s1, ls1, s2, ls2);
    bias_vals[o] = w;
    float pa = prior_lp(w);
    float qa = post_lp(w, pi_, s1, ls1, s2, ls2);
    #pragma unroll
    for (int off = 32; off; off >>= 1) {
        pa += __shfl_down(pa, off);
        qa += __shfl_down(qa, off);
    }
    const int wave = tid >> 6;
    if ((tid & 63) == 0) { red[wave] = pa; red[4 + wave] = qa; }
    __syncthreads();
    if (tid == 0) {
        bpart[2*blockIdx.x    ] = red[0] + red[1] + red[2] + red[3];
        bpart[2*blockIdx.x + 1] = red[4] + red[5] + red[6] + red[7];
    }
}

__global__ __launch_bounds__(256)
void bayes_reduce(float* __restrict__ out, const float* __restrict__ pbuf,
                  const float* __restrict__ bias, int nsplit)
{
    const size_t i = ((size_t)blockIdx.x * 256 + threadIdx.x) * 4;   // 1024 blocks
    const int o = (int)(i & (OUTN - 1));
    f4 a  = *(const f4*)&out[i];
    f4 bq = *(const f4*)&bias[o];
    #pragma unroll 1
    for (int s = 0; s < nsplit - 1; ++s) {
        f4 p = *(const f4*)&pbuf[(size_t)s * ((size_t)BN * OUTN) + i];
        #pragma unroll
        for (int j = 0; j < 4; ++j) a.v[j] += p.v[j];
    }
    #pragma unroll
    for (int j = 0; j < 4; ++j) a.v[j] += bq.v[j];
    *(f4*)&out[i] = a;
}

__global__ __launch_bounds__(256)
void bayes_final(const float* __restrict__ partials, int cnt,
                 float* __restrict__ out_scalars)
{
    __shared__ double sp[4], sq[4];
    const int tid = threadIdx.x;   // 256
    double p = 0.0, q = 0.0;
    for (int j = tid; j < cnt; j += 256) {
        p += (double)partials[2*j];
        q += (double)partials[2*j + 1];
    }
    #pragma unroll
    for (int off = 32; off; off >>= 1) {
        p += __shfl_down(p, off);
        q += __shfl_down(q, off);
    }
    const int wave = tid >> 6;
    if ((tid & 63) == 0) { sp[wave] = p; sq[wave] = q; }
    __syncthreads();
    if (tid == 0) {
        out_scalars[0] = (float)(sp[0] + sp[1] + sp[2] + sp[3]);
        out_scalars[1] = (float)(sq[0] + sq[1] + sq[2] + sq[3]);
    }
}

} // namespace

extern "C" void kernel_launch(void* const* d_in, const int* in_sizes, int n_in,
                              void* d_out, int out_size, void* d_ws, size_t ws_size,
                              hipStream_t stream) {
    (void)in_sizes; (void)n_in; (void)out_size;
    const float* x      = (const float*)d_in[0];
    const float* w_pi   = (const float*)d_in[1];
    const float* w_rho1 = (const float*)d_in[2];
    const float* w_rho2 = (const float*)d_in[3];
    const float* b_pi   = (const float*)d_in[4];
    const float* b_rho1 = (const float*)d_in[5];
    const float* b_rho2 = (const float*)d_in[6];
    const float* eps_w  = (const float*)d_in[7];
    const float* eps_b  = (const float*)d_in[8];
    const float* gum_w  = (const float*)d_in[9];
    const float* gum_b  = (const float*)d_in[10];

    float* out = (float*)d_out;
    float* ws  = (float*)d_ws;
    // ws layout (floats):
    //   [0, 8192)           bias values
    //   [8192, 24576)       logp partials: main blocks (2*512*NS) then bias blocks
    //   [24576, 286720)     x in bf16 (524288 shorts)
    //   [286720, ...)       (NS-1) partial GEMM outputs, 1048576 floats each
    float* bias_vals = ws;
    float* partials  = ws + 8192;
    short* xb        = (short*)(ws + 24576);
    float* pbuf      = ws + 286720;

    const size_t outElems = (size_t)BN * OUTN;
    int NS = 1;
    if      (ws_size >= (286720 + 7 * outElems) * sizeof(float)) NS = 8;
    else if (ws_size >= (286720 + 3 * outElems) * sizeof(float)) NS = 4;
    else if (ws_size >= (286720 + 1 * outElems) * sizeof(float)) NS = 2;

    float* bpart = partials + 2 * 512 * NS;
    const int cnt = 512 * NS + 32;

    xcast<<<(BN * INN) / (256 * 8), 256, 0, stream>>>(x, xb);
    bayes_bias<<<32, 256, 0, stream>>>(b_pi, b_rho1, b_rho2, eps_b, gum_b,
                                       bias_vals, bpart);

    if (NS == 1) {
        bayes_main<<<512, 64, 0, stream>>>(xb, w_pi, w_rho1, w_rho2, eps_w, gum_w,
                                           bias_vals, out, pbuf, partials, INN);
    } else {
        bayes_main<<<512 * NS, 64, 0, stream>>>(xb, w_pi, w_rho1, w_rho2, eps_w, gum_w,
                                                nullptr, out, pbuf, partials, INN / NS);
        bayes_reduce<<<(int)(outElems / 4 / 256), 256, 0, stream>>>(out, pbuf,
                                                                    bias_vals, NS);
    }
    bayes_final<<<1, 256, 0, stream>>>(partials, cnt, out + outElems);
}